// Round 17
// baseline (860.117 us; speedup 1.0000x reference)
//
#include <hip/hip_runtime.h>
#include <math.h>

#define NTOK   32768
#define DIMS   128
#define QST    8
#define KC     1024

#define SZ_QUANT (NTOK*DIMS)
#define SZ_CODES (NTOK*QST)
#define SZ_W     (QST*KC*DIMS)
#define OFF_CODES (SZ_QUANT)
#define OFF_LOSS  (OFF_CODES + SZ_CODES)
#define OFF_W     (OFF_LOSS + 1)
#define OFF_RM    (OFF_W + SZ_W)
#define OFF_CC    (OFF_RM + SZ_W)

#define MARGIN 0.02f            // 400 sigma of split-bf16 score error; top-2 exact verify
#define NKC 66                  // 528/8 fragment cells per code
#define CELLS_PER_CT (NKC*32)   // 2112 cells (16B each) per 32-code tile
#define CELLS_PER_STAGE (32*CELLS_PER_CT)
#define WSPLIT_FLOATS (QST*CELLS_PER_STAGE*4)
#define H0CELLS 1088            // half0: ks 0..16  (17 rows of 64 cells)
#define H1CELLS 1024            // half1: ks 17..32 (16 rows)

// d_ws float layout:
//  [0..16)          lacc[0]=loss acc; ((int*)ws)[8..16) = per-stage flag counts
//  [16..8208)       wsq  (Q*K)
//  [8208..40976)    kidx (int, N)
//  [40976..42000)   hist (int, K)
//  [42000..43024)   cursor (int, K)
//  [43024..75792)   sorted (int, N) packed (k<<15)|tok
//  [75792..108560)  flaglist (int, N) packed (k2<<15)|tok
//  [108560..632848) top2 (float4 per token per code-quarter, 2 MB)
//  [632848..2795536) wsplit (bf16 cells, 8.65 MB)
//  [.. )            rm replicas (2 x SZ_W floats), optional
#define WS_WSQ  16
#define WS_KIDX (WS_WSQ + QST*KC)
#define WS_HIST (WS_KIDX + NTOK)
#define WS_CUR  (WS_HIST + KC)
#define WS_SORT (WS_CUR + KC)
#define WS_FLAG (WS_SORT + NTOK)
#define WS_TOP2 (WS_FLAG + NTOK)
#define WS_WSPLIT (WS_TOP2 + 16*NTOK)
#define WS_RREP (WS_WSPLIT + WSPLIT_FLOATS)

typedef __attribute__((address_space(3))) float  lds_f;
typedef const __attribute__((address_space(1))) float gbl_f;
typedef __attribute__((ext_vector_type(8)))  short bf16x8;
typedef __attribute__((ext_vector_type(16))) float f32x16;

__device__ __forceinline__ unsigned short f2bf(float x) {
    unsigned int u = __float_as_uint(x);
    unsigned int r = (u + 0x7fffu + ((u >> 16) & 1u)) >> 16;
    return (unsigned short)r;
}
__device__ __forceinline__ float bf2f(unsigned short h) {
    return __uint_as_float(((unsigned int)h) << 16);
}

// ||w||^2 per code row (all stages)
__global__ void rvq_wsq(const float* __restrict__ w, float* __restrict__ wsq) {
    int row  = blockIdx.x * 4 + (threadIdx.x >> 6);
    int lane = threadIdx.x & 63;
    const float* wr = w + (size_t)row * DIMS;
    float a = wr[lane];
    float b = wr[lane + 64];
    float v = a * a + b * b;
    #pragma unroll
    for (int off = 32; off > 0; off >>= 1) v += __shfl_down(v, off, 64);
    if (lane == 0) wsq[row] = v;
}

// Build wsplit: per (s, ct, kc, code) a 16B cell of 8 bf16.
// Code-side K layout: [0,128)=hi(w) [128,256)=hi(w) [256,384)=lo(w) [384,512)=lo(w)
//                     k=512..514: 3-term bf16 split of -wsq/2 ; rest 0.
__global__ __launch_bounds__(256)
void rvq_prep_wsplit(const float* __restrict__ w, const float* __restrict__ wsq,
                     unsigned short* __restrict__ wsplit) {
    int cell = blockIdx.x * 256 + threadIdx.x;   // [0, 540672)
    int code = cell & 31;
    int c2   = cell >> 5;
    int kc   = c2 % NKC;
    int c3   = c2 / NKC;
    int ct   = c3 & 31;
    int s    = c3 >> 5;
    unsigned short out[8];
    int k0 = kc * 8;
    if (k0 < 512) {
        int region = k0 >> 7;           // 0,1 -> hi ; 2,3 -> lo
        int d0 = k0 & 127;
        const float* wr = w + ((size_t)s * KC + ct * 32 + code) * DIMS + d0;
        #pragma unroll
        for (int e = 0; e < 8; ++e) {
            float v = wr[e];
            unsigned short hu = f2bf(v);
            out[e] = (region < 2) ? hu : f2bf(v - bf2f(hu));
        }
    } else if (kc == 64) {
        float tq = -0.5f * wsq[s * KC + ct * 32 + code];
        unsigned short a = f2bf(tq);
        float fa = bf2f(a);
        unsigned short b = f2bf(tq - fa);
        float fb = bf2f(b);
        unsigned short c = f2bf(tq - fa - fb);
        out[0] = a; out[1] = b; out[2] = c;
        out[3] = out[4] = out[5] = out[6] = out[7] = 0;
    } else {
        #pragma unroll
        for (int e = 0; e < 8; ++e) out[e] = 0;
    }
    unsigned short* dst = wsplit + (size_t)cell * 8;
    #pragma unroll
    for (int e = 0; e < 8; ++e) dst[e] = out[e];
}

// MFMA distance + per-quarter top-2. Grid 1024: blockIdx = tok_blk*4 + ch.
// Block scans 8 tiles (256 codes) in 16 half-tile chunks.
// 34.8 KB LDS -> 4 blocks/CU (grid provides 4/CU now), 4 waves/SIMD.
__global__ __launch_bounds__(256, 4)
void rvq_dist_mfma(const float* __restrict__ rin,
                   const unsigned short* __restrict__ wsp,   // this stage's cells
                   float4* __restrict__ top2)                // [4][NTOK]
{
    __shared__ bf16x8 AT[2][H0CELLS];    // 2 x 17408 B = 34816 B

    const int bid  = blockIdx.x;
    const int ch   = bid & 3;            // code quarter: tiles ch*8 .. ch*8+7
    const int tb   = bid >> 2;
    const int t    = threadIdx.x;
    const int lane = t & 63;
    const int wid  = t >> 6;
    const int h    = lane >> 5;          // k-half
    const int ln32 = lane & 31;
    const int token = tb * 128 + wid * 32 + ln32;
    const int gt0  = ch * 8;

    // ---- load this lane's token data (its parity's 8 d-blocks) and build B-frags
    const float* rrow = rin + (size_t)token * DIMS;
    float4 R[16];
    #pragma unroll
    for (int j = 0; j < 8; ++j) {
        int d0 = (2 * j + h) * 8;
        R[2 * j]     = *reinterpret_cast<const float4*>(rrow + d0);
        R[2 * j + 1] = *reinterpret_cast<const float4*>(rrow + d0 + 4);
    }
    bf16x8 hb[8], lb[8];
    #pragma unroll
    for (int j = 0; j < 8; ++j) {
        float v[8] = {R[2*j].x, R[2*j].y, R[2*j].z, R[2*j].w,
                      R[2*j+1].x, R[2*j+1].y, R[2*j+1].z, R[2*j+1].w};
        #pragma unroll
        for (int e = 0; e < 8; ++e) {
            unsigned short hu = f2bf(v[e]);
            hb[j][e] = (short)hu;
            lb[j][e] = (short)f2bf(v[e] - bf2f(hu));
        }
    }
    // Token-side K layout: [0,128)=hi [128,256)=lo [256,384)=hi [384,512)=lo ; 512..514: 1.0
    bf16x8 bfr[33];
    #pragma unroll
    for (int fs = 0; fs < 32; ++fs) {
        int j = fs & 7;
        int region = fs >> 3;            // 0,2 -> hi ; 1,3 -> lo
        bfr[fs] = ((region & 1) == 0) ? hb[j] : lb[j];
    }
    {
        bf16x8 ones = {(short)0x3f80, (short)0x3f80, (short)0x3f80, 0, 0, 0, 0, 0};
        bf16x8 zero = {0, 0, 0, 0, 0, 0, 0, 0};
        bfr[32] = (h == 0) ? ones : zero;
    }

    // chunk c (0..15): tile tt=c>>1, half h2=c&1.
    // half0 = rows 0..16 (ks 0..16), half1 = rows 17..32.

    // ---- prologue: stage chunk 0
    {
        const unsigned short* src = wsp + (size_t)gt0 * CELLS_PER_CT * 8;
        unsigned short* dst = (unsigned short*)&AT[0][0];
        #pragma unroll 1
        for (int i = wid; i < 17; i += 4) {
            __builtin_amdgcn_global_load_lds(
                (gbl_f*)(src + (size_t)i * 512 + lane * 8),
                (lds_f*)(dst + (size_t)i * 512), 16, 0, 0);
        }
        asm volatile("s_waitcnt vmcnt(0)" ::: "memory");
    }
    __syncthreads();

    float b1 = -INFINITY, b2 = -INFINITY;
    int   k1 = 0, k2 = 0;
    f32x16 acc;

    #pragma unroll 1
    for (int c = 0; c < 16; ++c) {
        const int buf = c & 1;
        const int tt  = c >> 1;
        const int h2  = c & 1;
        if (c < 15) {                         // stage next chunk
            const int nc  = c + 1;
            const int ntt = nc >> 1, nh2 = nc & 1;
            const unsigned short* src = wsp +
                ((size_t)(gt0 + ntt) * CELLS_PER_CT + (nh2 ? H0CELLS : 0)) * 8;
            unsigned short* dst = (unsigned short*)&AT[buf ^ 1][0];
            const int nrows = nh2 ? 16 : 17;
            #pragma unroll 1
            for (int i = wid; i < nrows; i += 4) {
                __builtin_amdgcn_global_load_lds(
                    (gbl_f*)(src + (size_t)i * 512 + lane * 8),
                    (lds_f*)(dst + (size_t)i * 512), 16, 0, 0);
            }
        }

        if (h2 == 0) {
            #pragma unroll
            for (int e = 0; e < 16; ++e) acc[e] = 0.0f;
            const bf16x8* Ab = &AT[buf][lane];
            #pragma unroll
            for (int ks = 0; ks < 17; ++ks)
                acc = __builtin_amdgcn_mfma_f32_32x32x16_bf16(Ab[ks * 64], bfr[ks], acc, 0, 0, 0);
        } else {
            const bf16x8* Ab = &AT[buf][lane];
            #pragma unroll
            for (int ks = 0; ks < 16; ++ks)
                acc = __builtin_amdgcn_mfma_f32_32x32x16_bf16(Ab[ks * 64], bfr[17 + ks], acc, 0, 0, 0);

            // tile complete: running top-2 (score = dot - wsq/2 ; maximize)
            #pragma unroll
            for (int r = 0; r < 16; ++r) {
                float sc = acc[r];
                int   kk = (gt0 + tt) * 32 + ((r & 3) + 8 * (r >> 2) + 4 * h);
                bool  gt = sc > b1;
                bool  g2 = sc > b2;
                k2 = gt ? k1 : (g2 ? kk : k2);
                b2 = gt ? b1 : (g2 ? sc : b2);
                k1 = gt ? kk : k1;
                b1 = gt ? sc : b1;
            }
        }

        asm volatile("s_waitcnt vmcnt(0)" ::: "memory");
        __syncthreads();
    }

    // ---- merge the two k-halves of this token (lanes l <-> l+32)
    float ob1 = __shfl_xor(b1, 32, 64);
    float ob2 = __shfl_xor(b2, 32, 64);
    int   ok1 = __shfl_xor(k1, 32, 64);
    int   ok2 = __shfl_xor(k2, 32, 64);
    bool fw = (b1 > ob1) || (b1 == ob1 && k1 < ok1);
    float B1 = fw ? b1 : ob1;  int K1 = fw ? k1 : ok1;
    float c1 = fw ? ob1 : b1;  int c1k = fw ? ok1 : k1;   // loser's top
    float c2 = fw ? b2 : ob2;  int c2k = fw ? k2 : ok2;   // winner's second
    bool sw = (c1 > c2) || (c1 == c2 && c1k < c2k);
    float B2 = sw ? c1 : c2;   int K2 = sw ? c1k : c2k;

    if (h == 0) {
        float4 o = {B1, B2, __int_as_float(K1), __int_as_float(K2)};
        top2[(size_t)ch * NTOK + token] = o;
    }
}

// Merge the four code-quarter top2s (threads 0-63) + coalesced residual update.
// 512 blocks. No per-token device atomics (flagcnt wave-aggregated).
__global__ __launch_bounds__(256)
void rvq_merge(const float4* __restrict__ top2,
               const float* __restrict__ rin,
               float* __restrict__ rout,
               const float* __restrict__ wst,
               float* __restrict__ codes_out,
               int* __restrict__ kidx,
               int* __restrict__ flaglist,
               int* __restrict__ flagcnt,
               int stage)
{
    __shared__ int kb[64];
    const int t    = threadIdx.x;
    const int tok0 = blockIdx.x * 64;

    if (t < 64) {                         // exactly wave 0
        const int token = tok0 + t;
        float4 q0 = top2[token];
        float B1 = q0.x, B2 = q0.y;
        int   K1 = __float_as_int(q0.z), K2 = __float_as_int(q0.w);
        #pragma unroll
        for (int i = 1; i < 4; ++i) {
            float4 qi = top2[(size_t)i * NTOK + token];
            float c1 = qi.x, c2 = qi.y;
            int  ck1 = __float_as_int(qi.z), ck2 = __float_as_int(qi.w);
            bool fw = (B1 > c1) || (B1 == c1 && K1 < ck1);
            float nB1 = fw ? B1 : c1;  int nK1 = fw ? K1 : ck1;
            float l1  = fw ? c1 : B1;  int l1k = fw ? ck1 : K1;   // loser's top
            float w2  = fw ? B2 : c2;  int w2k = fw ? K2 : ck2;   // winner's second
            bool sw = (l1 > w2) || (l1 == w2 && l1k < w2k);
            B1 = nB1; K1 = nK1;
            B2 = sw ? l1 : w2;  K2 = sw ? l1k : w2k;
        }

        kidx[token] = K1;
        codes_out[(size_t)token * QST + stage] = (float)K1;
        kb[t] = K1;

        bool flg = (B1 - B2 < MARGIN);
        unsigned long long mask = __ballot(flg);
        int base = 0;
        if (t == 0 && mask) base = atomicAdd(flagcnt, (int)__popcll(mask));
        base = __shfl(base, 0, 64);
        if (flg) {
            int off = (int)__popcll(mask & ((1ULL << t) - 1ULL));
            flaglist[base + off] = (K2 << 15) | token;
        }
    }
    __syncthreads();

    // residual update: rout = rin - w[K1]; 64 tok x 32 float4, coalesced
    #pragma unroll
    for (int it = 0; it < 8; ++it) {
        int idx = it * 256 + t;
        int tok = idx >> 5;
        int dq  = idx & 31;
        int k   = kb[tok];
        float4 rv = *reinterpret_cast<const float4*>(rin + (size_t)(tok0 + tok) * DIMS + dq * 4);
        float4 wv = *reinterpret_cast<const float4*>(wst + (size_t)k * DIMS + dq * 4);
        float4 o = {rv.x - wv.x, rv.y - wv.y, rv.z - wv.z, rv.w - wv.w};
        *reinterpret_cast<float4*>(rout + (size_t)(tok0 + tok) * DIMS + dq * 4) = o;
    }
}

// Exact fp32 top-2 verify for flagged tokens: one wave per token.
// r_old reconstructed as rout + w[k1]; patches kidx/codes/rout on flip.
__global__ __launch_bounds__(256)
void rvq_rescore2(float* __restrict__ rq,
                  const float* __restrict__ wst,
                  const float* __restrict__ wsqst,
                  const int* __restrict__ flaglist,
                  const int* __restrict__ flagcnt,
                  int* __restrict__ kidx,
                  float* __restrict__ codes_out,
                  int stage)
{
    const int cnt  = *flagcnt;
    const int lane = threadIdx.x & 63;
    const int wave = blockIdx.x * 4 + (threadIdx.x >> 6);
    const int nw   = gridDim.x * 4;

    for (int f = wave; f < cnt; f += nw) {
        int e   = flaglist[f];
        int tok = e & 32767;
        int k2  = e >> 15;
        int k1  = kidx[tok];
        float rn0 = rq[(size_t)tok * DIMS + lane];
        float rn1 = rq[(size_t)tok * DIMS + 64 + lane];
        float w10 = wst[(size_t)k1 * DIMS + lane];
        float w11 = wst[(size_t)k1 * DIMS + 64 + lane];
        float w20 = wst[(size_t)k2 * DIMS + lane];
        float w21 = wst[(size_t)k2 * DIMS + 64 + lane];
        float r0 = rn0 + w10, r1 = rn1 + w11;       // r_old
        float d1 = r0 * w10 + r1 * w11;
        float d2 = r0 * w20 + r1 * w21;
        #pragma unroll
        for (int off = 32; off > 0; off >>= 1) {
            d1 += __shfl_xor(d1, off, 64);
            d2 += __shfl_xor(d2, off, 64);
        }
        float s1 = wsqst[k1] - 2.0f * d1;
        float s2 = wsqst[k2] - 2.0f * d2;
        bool flip = (s2 < s1) || (s2 == s1 && k2 < k1);
        if (flip) {
            rq[(size_t)tok * DIMS + lane]      = r0 - w20;
            rq[(size_t)tok * DIMS + 64 + lane] = r1 - w21;
            if (lane == 0) {
                kidx[tok] = k2;
                codes_out[(size_t)tok * QST + stage] = (float)k2;
            }
        }
    }
}

// Histogram of final codes: 32 blocks x 256 threads, LDS-privatized.
__global__ __launch_bounds__(256)
void rvq_histo(const int* __restrict__ kidx, int* __restrict__ hist) {
    __shared__ int lh[KC];
    const int t = threadIdx.x;
    #pragma unroll
    for (int rep = 0; rep < 4; ++rep) lh[rep * 256 + t] = 0;
    __syncthreads();
    int base = blockIdx.x * 1024;
    #pragma unroll
    for (int rep = 0; rep < 4; ++rep) {
        int k = kidx[base + rep * 256 + t];
        atomicAdd(&lh[k], 1);
    }
    __syncthreads();
    #pragma unroll
    for (int rep = 0; rep < 4; ++rep) {
        int bin = rep * 256 + t;
        int c = lh[bin];
        if (c) atomicAdd(&hist[bin], c);
    }
}

// Exclusive scan of hist -> cursor; finalizes code_count; re-zeroes hist.
__global__ __launch_bounds__(1024)
void rvq_scan(int* __restrict__ hist, int* __restrict__ cursor,
              const float* __restrict__ cc_in, float* __restrict__ cc_io,
              int stage) {
    __shared__ int s[KC];
    const int t = threadIdx.x;
    int h = hist[t];
    hist[t] = 0;                          // ready for next stage
    s[t] = h;
    __syncthreads();
    for (int off = 1; off < KC; off <<= 1) {
        int v = (t >= off) ? s[t - off] : 0;
        __syncthreads();
        s[t] += v;
        __syncthreads();
    }
    cursor[t] = s[t] - h;
    size_t gi = (size_t)stage * KC + t;
    cc_io[gi] = cc_in[gi] * 0.99f + ((float)h / 32768.0f) * 0.01f;
}

// Rank-based counting-sort scatter: 128 blocks x 256 threads.
__global__ __launch_bounds__(256)
void rvq_scatter(const int* __restrict__ kidx, int* __restrict__ cursor,
                 int* __restrict__ sorted) {
    __shared__ int lh[KC];
    __shared__ int lb[KC];
    const int t = threadIdx.x;
    #pragma unroll
    for (int rep = 0; rep < 4; ++rep) lh[rep * 256 + t] = 0;
    __syncthreads();
    int tok = blockIdx.x * 256 + t;
    int k   = kidx[tok];
    int lr  = atomicAdd(&lh[k], 1);
    __syncthreads();
    #pragma unroll
    for (int rep = 0; rep < 4; ++rep) {
        int bin = rep * 256 + t;
        int c = lh[bin];
        if (c) lb[bin] = atomicAdd(&cursor[bin], c);
    }
    __syncthreads();
    int pos = lb[k] + lr;
    sorted[pos] = (k << 15) | tok;
}

// Segmented sum over sorted tokens, reconstructing r_old = r_new + w[k]:
// sum(r_old over run) = sum(r_new) + count*w[k]. Run-boundary atomics only.
__global__ __launch_bounds__(128)
void rvq_segsum(const float* __restrict__ rq,
                const int* __restrict__ sorted,
                const float* __restrict__ wst,
                float* __restrict__ rm0,
                float* __restrict__ repbuf,
                int nrep)
{
    __shared__ int pc[64];
    const int t = threadIdx.x;
    if (t < 64) pc[t] = sorted[blockIdx.x * 64 + t];
    __syncthreads();

    int rep = (int)(blockIdx.x % (unsigned)nrep);
    float* rmt = (rep == 0) ? rm0 : repbuf + (size_t)(rep - 1) * SZ_W;

    const int d = t;
    int   cur = pc[0] >> 15;
    float acc = 0.0f;
    float lc  = 0.0f;
    #pragma unroll 4
    for (int i = 0; i < 64; ++i) {
        int v   = pc[i];
        int c   = v >> 15;
        int tok = v & 32767;
        if (c != cur) {
            atomicAdd(rmt + (size_t)cur * DIMS + d,
                      acc + lc * wst[(size_t)cur * DIMS + d]);
            acc = 0.0f; lc = 0.0f;
            cur = c;
        }
        acc += rq[(size_t)tok * DIMS + d];
        lc  += 1.0f;
    }
    atomicAdd(rmt + (size_t)cur * DIMS + d,
              acc + lc * wst[(size_t)cur * DIMS + d]);
}

// quantized = x - r (in place) + commitment-loss partials
__global__ void rvq_quant_loss(const float* __restrict__ x,
                               float* __restrict__ rq,
                               float* __restrict__ loss_acc) {
    __shared__ float ws[4];
    int tid = blockIdx.x * 256 + threadIdx.x;
    float lsum = 0.0f;
    #pragma unroll
    for (int rep = 0; rep < 4; ++rep) {
        size_t q = (size_t)tid + (size_t)rep * 262144;
        float4 rv = *reinterpret_cast<float4*>(rq + q * 4);
        float4 xv = *reinterpret_cast<const float4*>(x + q * 4);
        lsum += rv.x*rv.x + rv.y*rv.y + rv.z*rv.z + rv.w*rv.w;
        float4 o = {xv.x - rv.x, xv.y - rv.y, xv.z - rv.z, xv.w - rv.w};
        *reinterpret_cast<float4*>(rq + q * 4) = o;
    }
    #pragma unroll
    for (int off = 32; off > 0; off >>= 1) lsum += __shfl_down(lsum, off, 64);
    if ((threadIdx.x & 63) == 0) ws[threadIdx.x >> 6] = lsum;
    __syncthreads();
    if (threadIdx.x == 0) atomicAdd(loss_acc, ws[0] + ws[1] + ws[2] + ws[3]);
}

__global__ void rvq_fin_rmw(const float* __restrict__ rm_in,
                            float* __restrict__ rm_io,
                            const float* __restrict__ ws_rm,
                            int nrep_m1,
                            float* __restrict__ w_out,
                            const float* __restrict__ cc_fin,
                            const float* __restrict__ loss_acc,
                            float* __restrict__ loss_out) {
    int i = blockIdx.x * 256 + threadIdx.x;
    float a = rm_io[i];
    for (int r = 0; r < nrep_m1; ++r) a += ws_rm[(size_t)r * SZ_W + i];
    float nrm = rm_in[i] * 0.99f + (a / 32768.0f) * 0.01f;
    rm_io[i] = nrm;
    w_out[i] = nrm / (1e-10f + cc_fin[i >> 7]);
    if (i == 0) loss_out[0] = loss_acc[0] / (float)(NTOK * DIMS);
}

extern "C" void kernel_launch(void* const* d_in, const int* in_sizes, int n_in,
                              void* d_out, int out_size, void* d_ws, size_t ws_size,
                              hipStream_t stream) {
    const float* x   = (const float*)d_in[0];
    const float* w   = (const float*)d_in[1];
    const float* rm  = (const float*)d_in[2];
    const float* cc  = (const float*)d_in[3];
    float* out   = (float*)d_out;
    float* quant = out;
    float* codes = out + OFF_CODES;
    float* loss  = out + OFF_LOSS;
    float* wout  = out + OFF_W;
    float* rmout = out + OFF_RM;
    float* ccout = out + OFF_CC;
    float* wsf   = (float*)d_ws;
    float* lacc  = wsf;
    int*   flagcnt = (int*)(wsf) + 8;           // 8 per-stage slots
    float* wsq   = wsf + WS_WSQ;
    int*   kidx  = (int*)(wsf + WS_KIDX);
    int*   hist  = (int*)(wsf + WS_HIST);
    int*   cursor= (int*)(wsf + WS_CUR);
    int*   sorted= (int*)(wsf + WS_SORT);
    int*   flaglist = (int*)(wsf + WS_FLAG);
    float4* top2 = (float4*)(wsf + WS_TOP2);
    unsigned short* wsplit = (unsigned short*)(wsf + WS_WSPLIT);
    float* repbuf= wsf + WS_RREP;

    int nrep = 1;
    if (ws_size >= (size_t)(WS_RREP + 2 * SZ_W) * sizeof(float)) nrep = 3;

    hipMemsetAsync(rmout, 0, (size_t)SZ_W * sizeof(float), stream);
    hipMemsetAsync(d_ws, 0, 16 * sizeof(float), stream);  // lacc + 8 flagcnt slots
    hipMemsetAsync(hist, 0, KC * sizeof(int), stream);    // once; scan re-zeroes
    if (nrep > 1)
        hipMemsetAsync(repbuf, 0, (size_t)2 * SZ_W * sizeof(float), stream);

    rvq_wsq<<<QST * KC / 4, 256, 0, stream>>>(w, wsq);
    rvq_prep_wsplit<<<QST * CELLS_PER_STAGE / 256, 256, 0, stream>>>(w, wsq, wsplit);

    for (int s = 0; s < QST; ++s) {
        const float* rin = (s == 0) ? x : quant;
        rvq_dist_mfma<<<NTOK / 128 * 4, 256, 0, stream>>>(
            rin,
            wsplit + (size_t)s * CELLS_PER_STAGE * 8,
            top2);
        rvq_merge<<<NTOK / 64, 256, 0, stream>>>(
            top2, rin, quant,
            w + (size_t)s * KC * DIMS,
            codes, kidx, flaglist, flagcnt + s, s);
        rvq_rescore2<<<256, 256, 0, stream>>>(
            quant,
            w + (size_t)s * KC * DIMS,
            wsq + (size_t)s * KC,
            flaglist, flagcnt + s, kidx, codes, s);
        rvq_histo<<<32, 256, 0, stream>>>(kidx, hist);
        rvq_scan<<<1, 1024, 0, stream>>>(hist, cursor, cc, ccout, s);
        rvq_scatter<<<128, 256, 0, stream>>>(kidx, cursor, sorted);
        rvq_segsum<<<NTOK / 64, 128, 0, stream>>>(
            quant, sorted,
            w + (size_t)s * KC * DIMS,
            rmout + (size_t)s * KC * DIMS,
            repbuf + (size_t)s * KC * DIMS,
            nrep);
    }

    rvq_quant_loss<<<1024, 256, 0, stream>>>(x, quant, lacc);
    rvq_fin_rmw<<<SZ_W / 256, 256, 0, stream>>>(rm, rmout, repbuf, nrep - 1,
                                                wout, ccout, lacc, loss);
}

// Round 18
// 799.281 us; speedup vs baseline: 1.0761x; 1.0761x over previous
//
#include <hip/hip_runtime.h>
#include <math.h>

#define NTOK   32768
#define DIMS   128
#define QST    8
#define KC     1024

#define SZ_QUANT (NTOK*DIMS)
#define SZ_CODES (NTOK*QST)
#define SZ_W     (QST*KC*DIMS)
#define OFF_CODES (SZ_QUANT)
#define OFF_LOSS  (OFF_CODES + SZ_CODES)
#define OFF_W     (OFF_LOSS + 1)
#define OFF_RM    (OFF_W + SZ_W)
#define OFF_CC    (OFF_RM + SZ_W)

#define MARGIN 0.02f            // 400 sigma of split-bf16 score error; top-2 exact verify
#define NKC 66                  // 528/8 fragment cells per code
#define CELLS_PER_CT (NKC*32)   // 2112 cells (16B each) per 32-code tile
#define CELLS_PER_STAGE (32*CELLS_PER_CT)
#define WSPLIT_FLOATS (QST*CELLS_PER_STAGE*4)

// d_ws float layout (R15 layout; hist slot unused now):
#define WS_WSQ  16
#define WS_KIDX (WS_WSQ + QST*KC)
#define WS_HIST (WS_KIDX + NTOK)
#define WS_CUR  (WS_HIST + KC)
#define WS_SORT (WS_CUR + KC)
#define WS_FLAG (WS_SORT + NTOK)
#define WS_TOP2 (WS_FLAG + NTOK)
#define WS_WSPLIT (WS_TOP2 + 8*NTOK)
#define WS_RREP (WS_WSPLIT + WSPLIT_FLOATS)

typedef __attribute__((address_space(3))) float  lds_f;
typedef const __attribute__((address_space(1))) float gbl_f;
typedef __attribute__((ext_vector_type(8)))  short bf16x8;
typedef __attribute__((ext_vector_type(16))) float f32x16;

__device__ __forceinline__ unsigned short f2bf(float x) {
    unsigned int u = __float_as_uint(x);
    unsigned int r = (u + 0x7fffu + ((u >> 16) & 1u)) >> 16;
    return (unsigned short)r;
}
__device__ __forceinline__ float bf2f(unsigned short h) {
    return __uint_as_float(((unsigned int)h) << 16);
}

// ||w||^2 per code row (all stages)
__global__ void rvq_wsq(const float* __restrict__ w, float* __restrict__ wsq) {
    int row  = blockIdx.x * 4 + (threadIdx.x >> 6);
    int lane = threadIdx.x & 63;
    const float* wr = w + (size_t)row * DIMS;
    float a = wr[lane];
    float b = wr[lane + 64];
    float v = a * a + b * b;
    #pragma unroll
    for (int off = 32; off > 0; off >>= 1) v += __shfl_down(v, off, 64);
    if (lane == 0) wsq[row] = v;
}

// Build wsplit: per (s, ct, kc, code) a 16B cell of 8 bf16.
// Code-side K layout: [0,128)=hi(w) [128,256)=hi(w) [256,384)=lo(w) [384,512)=lo(w)
//                     k=512..514: 3-term bf16 split of -wsq/2 ; rest 0.
__global__ __launch_bounds__(256)
void rvq_prep_wsplit(const float* __restrict__ w, const float* __restrict__ wsq,
                     unsigned short* __restrict__ wsplit) {
    int cell = blockIdx.x * 256 + threadIdx.x;   // [0, 540672)
    int code = cell & 31;
    int c2   = cell >> 5;
    int kc   = c2 % NKC;
    int c3   = c2 / NKC;
    int ct   = c3 & 31;
    int s    = c3 >> 5;
    unsigned short out[8];
    int k0 = kc * 8;
    if (k0 < 512) {
        int region = k0 >> 7;           // 0,1 -> hi ; 2,3 -> lo
        int d0 = k0 & 127;
        const float* wr = w + ((size_t)s * KC + ct * 32 + code) * DIMS + d0;
        #pragma unroll
        for (int e = 0; e < 8; ++e) {
            float v = wr[e];
            unsigned short hu = f2bf(v);
            out[e] = (region < 2) ? hu : f2bf(v - bf2f(hu));
        }
    } else if (kc == 64) {
        float tq = -0.5f * wsq[s * KC + ct * 32 + code];
        unsigned short a = f2bf(tq);
        float fa = bf2f(a);
        unsigned short b = f2bf(tq - fa);
        float fb = bf2f(b);
        unsigned short c = f2bf(tq - fa - fb);
        out[0] = a; out[1] = b; out[2] = c;
        out[3] = out[4] = out[5] = out[6] = out[7] = 0;
    } else {
        #pragma unroll
        for (int e = 0; e < 8; ++e) out[e] = 0;
    }
    unsigned short* dst = wsplit + (size_t)cell * 8;
    #pragma unroll
    for (int e = 0; e < 8; ++e) dst[e] = out[e];
}

// MFMA distance + per-half top-2. Grid 512: blockIdx = tok_blk*2 + ch.
// Block = 256 thr = 4 waves; wave owns 32 tokens; block scans 16 tiles (512 codes).
// 2 blocks/CU (LDS 67.5 KB) -> 2 waves/SIMD. [R15 exact configuration]
__global__ __launch_bounds__(256, 2)
void rvq_dist_mfma(const float* __restrict__ rin,
                   const unsigned short* __restrict__ wsp,   // this stage's cells
                   float4* __restrict__ top2)                // [2][NTOK]
{
    __shared__ bf16x8 AT[2][CELLS_PER_CT];   // 2 x 33792 B

    const int bid  = blockIdx.x;
    const int ch   = bid & 1;            // code half: tiles ch*16 .. ch*16+15
    const int tb   = bid >> 1;
    const int t    = threadIdx.x;
    const int lane = t & 63;
    const int wid  = t >> 6;
    const int h    = lane >> 5;          // k-half
    const int ln32 = lane & 31;
    const int token = tb * 128 + wid * 32 + ln32;
    const int gt0  = ch * 16;

    // ---- load this lane's token data (its parity's 8 d-blocks) and build B-frags
    const float* rrow = rin + (size_t)token * DIMS;
    float4 R[16];
    #pragma unroll
    for (int j = 0; j < 8; ++j) {
        int d0 = (2 * j + h) * 8;
        R[2 * j]     = *reinterpret_cast<const float4*>(rrow + d0);
        R[2 * j + 1] = *reinterpret_cast<const float4*>(rrow + d0 + 4);
    }
    bf16x8 hb[8], lb[8];
    #pragma unroll
    for (int j = 0; j < 8; ++j) {
        float v[8] = {R[2*j].x, R[2*j].y, R[2*j].z, R[2*j].w,
                      R[2*j+1].x, R[2*j+1].y, R[2*j+1].z, R[2*j+1].w};
        #pragma unroll
        for (int e = 0; e < 8; ++e) {
            unsigned short hu = f2bf(v[e]);
            hb[j][e] = (short)hu;
            lb[j][e] = (short)f2bf(v[e] - bf2f(hu));
        }
    }
    // Token-side K layout: [0,128)=hi [128,256)=lo [256,384)=hi [384,512)=lo ; 512..514: 1.0
    bf16x8 bfr[33];
    #pragma unroll
    for (int fs = 0; fs < 32; ++fs) {
        int j = fs & 7;
        int region = fs >> 3;            // 0,2 -> hi ; 1,3 -> lo
        bfr[fs] = ((region & 1) == 0) ? hb[j] : lb[j];
    }
    {
        bf16x8 ones = {(short)0x3f80, (short)0x3f80, (short)0x3f80, 0, 0, 0, 0, 0};
        bf16x8 zero = {0, 0, 0, 0, 0, 0, 0, 0};
        bfr[32] = (h == 0) ? ones : zero;
    }

    // ---- prologue: stage first tile
    {
        const unsigned short* src = wsp + (size_t)gt0 * CELLS_PER_CT * 8;
        #pragma unroll 1
        for (int i = wid; i < 33; i += 4) {
            __builtin_amdgcn_global_load_lds(
                (gbl_f*)(src + (size_t)i * 512 + lane * 8),
                (lds_f*)((unsigned short*)&AT[0][i * 64]), 16, 0, 0);
        }
        asm volatile("s_waitcnt vmcnt(0)" ::: "memory");
    }
    __syncthreads();

    float b1 = -INFINITY, b2 = -INFINITY;
    int   k1 = 0, k2 = 0;

    #pragma unroll 1
    for (int tt = 0; tt < 16; ++tt) {
        const int buf = tt & 1;
        if (tt < 15) {                        // stage next tile
            const unsigned short* src = wsp + (size_t)(gt0 + tt + 1) * CELLS_PER_CT * 8;
            #pragma unroll 1
            for (int i = wid; i < 33; i += 4) {
                __builtin_amdgcn_global_load_lds(
                    (gbl_f*)(src + (size_t)i * 512 + lane * 8),
                    (lds_f*)((unsigned short*)&AT[buf ^ 1][i * 64]), 16, 0, 0);
            }
        }

        f32x16 acc;
        #pragma unroll
        for (int e = 0; e < 16; ++e) acc[e] = 0.0f;

        const bf16x8* Ab = &AT[buf][lane];    // cell = 64*ks + lane
        #pragma unroll
        for (int ks = 0; ks < 33; ++ks) {
            bf16x8 af = Ab[ks * 64];
            acc = __builtin_amdgcn_mfma_f32_32x32x16_bf16(af, bfr[ks], acc, 0, 0, 0);
        }

        // running top-2 (score = dot - wsq/2 ; maximize)
        #pragma unroll
        for (int r = 0; r < 16; ++r) {
            float sc = acc[r];
            int   kk = (gt0 + tt) * 32 + ((r & 3) + 8 * (r >> 2) + 4 * h);
            bool  gt = sc > b1;
            bool  g2 = sc > b2;
            k2 = gt ? k1 : (g2 ? kk : k2);
            b2 = gt ? b1 : (g2 ? sc : b2);
            k1 = gt ? kk : k1;
            b1 = gt ? sc : b1;
        }

        asm volatile("s_waitcnt vmcnt(0)" ::: "memory");
        __syncthreads();
    }

    // ---- merge the two k-halves of this token (lanes l <-> l+32)
    float ob1 = __shfl_xor(b1, 32, 64);
    float ob2 = __shfl_xor(b2, 32, 64);
    int   ok1 = __shfl_xor(k1, 32, 64);
    int   ok2 = __shfl_xor(k2, 32, 64);
    bool fw = (b1 > ob1) || (b1 == ob1 && k1 < ok1);
    float B1 = fw ? b1 : ob1;  int K1 = fw ? k1 : ok1;
    float c1 = fw ? ob1 : b1;  int c1k = fw ? ok1 : k1;   // loser's top
    float c2 = fw ? b2 : ob2;  int c2k = fw ? k2 : ok2;   // winner's second
    bool sw = (c1 > c2) || (c1 == c2 && c1k < c2k);
    float B2 = sw ? c1 : c2;   int K2 = sw ? c1k : c2k;

    if (h == 0) {
        float4 o = {B1, B2, __int_as_float(K1), __int_as_float(K2)};
        top2[(size_t)ch * NTOK + token] = o;
    }
}

// Merge the two code-half top2s (threads 0-63) + coalesced residual update.
// 512 blocks. No per-token device atomics (flagcnt wave-aggregated).
__global__ __launch_bounds__(256)
void rvq_merge(const float4* __restrict__ top2,
               const float* __restrict__ rin,
               float* __restrict__ rout,
               const float* __restrict__ wst,
               float* __restrict__ codes_out,
               int* __restrict__ kidx,
               int* __restrict__ flaglist,
               int* __restrict__ flagcnt,
               int stage)
{
    __shared__ int kb[64];
    const int t    = threadIdx.x;
    const int tok0 = blockIdx.x * 64;

    if (t < 64) {                         // exactly wave 0
        const int token = tok0 + t;
        float4 a = top2[token];
        float4 b = top2[NTOK + token];
        float a1 = a.x, a2 = a.y; int ak1 = __float_as_int(a.z), ak2 = __float_as_int(a.w);
        float c1 = b.x, c2 = b.y; int bk1 = __float_as_int(b.z), bk2 = __float_as_int(b.w);
        bool fw = (a1 > c1) || (a1 == c1 && ak1 < bk1);
        float B1 = fw ? a1 : c1;  int K1 = fw ? ak1 : bk1;
        float l1 = fw ? c1 : a1;  int l1k = fw ? bk1 : ak1;   // loser's top
        float w2 = fw ? a2 : c2;  int w2k = fw ? ak2 : bk2;   // winner's second
        bool sw = (l1 > w2) || (l1 == w2 && l1k < w2k);
        float B2 = sw ? l1 : w2;  int K2 = sw ? l1k : w2k;

        kidx[token] = K1;
        codes_out[(size_t)token * QST + stage] = (float)K1;
        kb[t] = K1;

        bool flg = (B1 - B2 < MARGIN);
        unsigned long long mask = __ballot(flg);
        int base = 0;
        if (t == 0 && mask) base = atomicAdd(flagcnt, (int)__popcll(mask));
        base = __shfl(base, 0, 64);
        if (flg) {
            int off = (int)__popcll(mask & ((1ULL << t) - 1ULL));
            flaglist[base + off] = (K2 << 15) | token;
        }
    }
    __syncthreads();

    // residual update: rout = rin - w[K1]; 64 tok x 32 float4, coalesced
    #pragma unroll
    for (int it = 0; it < 8; ++it) {
        int idx = it * 256 + t;
        int tok = idx >> 5;
        int dq  = idx & 31;
        int k   = kb[tok];
        float4 rv = *reinterpret_cast<const float4*>(rin + (size_t)(tok0 + tok) * DIMS + dq * 4);
        float4 wv = *reinterpret_cast<const float4*>(wst + (size_t)k * DIMS + dq * 4);
        float4 o = {rv.x - wv.x, rv.y - wv.y, rv.z - wv.z, rv.w - wv.w};
        *reinterpret_cast<float4*>(rout + (size_t)(tok0 + tok) * DIMS + dq * 4) = o;
    }
}

// Exact fp32 top-2 verify for flagged tokens: one wave per token.
// r_old reconstructed as rout + w[k1]; patches kidx/codes/rout on flip.
__global__ __launch_bounds__(256)
void rvq_rescore2(float* __restrict__ rq,
                  const float* __restrict__ wst,
                  const float* __restrict__ wsqst,
                  const int* __restrict__ flaglist,
                  const int* __restrict__ flagcnt,
                  int* __restrict__ kidx,
                  float* __restrict__ codes_out,
                  int stage)
{
    const int cnt  = *flagcnt;
    const int lane = threadIdx.x & 63;
    const int wave = blockIdx.x * 4 + (threadIdx.x >> 6);
    const int nw   = gridDim.x * 4;

    for (int f = wave; f < cnt; f += nw) {
        int e   = flaglist[f];
        int tok = e & 32767;
        int k2  = e >> 15;
        int k1  = kidx[tok];
        float rn0 = rq[(size_t)tok * DIMS + lane];
        float rn1 = rq[(size_t)tok * DIMS + 64 + lane];
        float w10 = wst[(size_t)k1 * DIMS + lane];
        float w11 = wst[(size_t)k1 * DIMS + 64 + lane];
        float w20 = wst[(size_t)k2 * DIMS + lane];
        float w21 = wst[(size_t)k2 * DIMS + 64 + lane];
        float r0 = rn0 + w10, r1 = rn1 + w11;       // r_old
        float d1 = r0 * w10 + r1 * w11;
        float d2 = r0 * w20 + r1 * w21;
        #pragma unroll
        for (int off = 32; off > 0; off >>= 1) {
            d1 += __shfl_xor(d1, off, 64);
            d2 += __shfl_xor(d2, off, 64);
        }
        float s1 = wsqst[k1] - 2.0f * d1;
        float s2 = wsqst[k2] - 2.0f * d2;
        bool flip = (s2 < s1) || (s2 == s1 && k2 < k1);
        if (flip) {
            rq[(size_t)tok * DIMS + lane]      = r0 - w20;
            rq[(size_t)tok * DIMS + 64 + lane] = r1 - w21;
            if (lane == 0) {
                kidx[tok] = k2;
                codes_out[(size_t)tok * QST + stage] = (float)k2;
            }
        }
    }
}

// Fused histogram + exclusive scan (single block, 1024 threads).
// LDS-private histogram (no global hist buffer / memset / extra launch);
// writes cursor + finalizes code_count. Scatter stays separate (R10 lesson:
// fusing the scatter too is what regressed).
__global__ __launch_bounds__(1024)
void rvq_histscan(const int* __restrict__ kidx, int* __restrict__ cursor,
                  const float* __restrict__ cc_in, float* __restrict__ cc_io,
                  int stage)
{
    __shared__ int lh[KC];
    __shared__ int s[KC];
    const int t = threadIdx.x;
    lh[t] = 0;
    __syncthreads();
    #pragma unroll
    for (int i = 0; i < 32; ++i) {
        int k = kidx[i * 1024 + t];
        atomicAdd(&lh[k], 1);
    }
    __syncthreads();
    int h = lh[t];
    s[t] = h;
    __syncthreads();
    for (int off = 1; off < KC; off <<= 1) {
        int v = (t >= off) ? s[t - off] : 0;
        __syncthreads();
        s[t] += v;
        __syncthreads();
    }
    cursor[t] = s[t] - h;
    size_t gi = (size_t)stage * KC + t;
    cc_io[gi] = cc_in[gi] * 0.99f + ((float)h / 32768.0f) * 0.01f;
}

// Rank-based counting-sort scatter: 128 blocks x 256 threads.
__global__ __launch_bounds__(256)
void rvq_scatter(const int* __restrict__ kidx, int* __restrict__ cursor,
                 int* __restrict__ sorted) {
    __shared__ int lh[KC];
    __shared__ int lb[KC];
    const int t = threadIdx.x;
    #pragma unroll
    for (int rep = 0; rep < 4; ++rep) lh[rep * 256 + t] = 0;
    __syncthreads();
    int tok = blockIdx.x * 256 + t;
    int k   = kidx[tok];
    int lr  = atomicAdd(&lh[k], 1);
    __syncthreads();
    #pragma unroll
    for (int rep = 0; rep < 4; ++rep) {
        int bin = rep * 256 + t;
        int c = lh[bin];
        if (c) lb[bin] = atomicAdd(&cursor[bin], c);
    }
    __syncthreads();
    int pos = lb[k] + lr;
    sorted[pos] = (k << 15) | tok;
}

// Segmented sum over sorted tokens, reconstructing r_old = r_new + w[k]:
// sum(r_old over run) = sum(r_new) + count*w[k]. Run-boundary atomics only.
__global__ __launch_bounds__(128)
void rvq_segsum(const float* __restrict__ rq,
                const int* __restrict__ sorted,
                const float* __restrict__ wst,
                float* __restrict__ rm0,
                float* __restrict__ repbuf,
                int nrep)
{
    __shared__ int pc[64];
    const int t = threadIdx.x;
    if (t < 64) pc[t] = sorted[blockIdx.x * 64 + t];
    __syncthreads();

    int rep = (int)(blockIdx.x % (unsigned)nrep);
    float* rmt = (rep == 0) ? rm0 : repbuf + (size_t)(rep - 1) * SZ_W;

    const int d = t;
    int   cur = pc[0] >> 15;
    float acc = 0.0f;
    float lc  = 0.0f;
    #pragma unroll 4
    for (int i = 0; i < 64; ++i) {
        int v   = pc[i];
        int c   = v >> 15;
        int tok = v & 32767;
        if (c != cur) {
            atomicAdd(rmt + (size_t)cur * DIMS + d,
                      acc + lc * wst[(size_t)cur * DIMS + d]);
            acc = 0.0f; lc = 0.0f;
            cur = c;
        }
        acc += rq[(size_t)tok * DIMS + d];
        lc  += 1.0f;
    }
    atomicAdd(rmt + (size_t)cur * DIMS + d,
              acc + lc * wst[(size_t)cur * DIMS + d]);
}

// quantized = x - r (in place) + commitment-loss partials
__global__ void rvq_quant_loss(const float* __restrict__ x,
                               float* __restrict__ rq,
                               float* __restrict__ loss_acc) {
    __shared__ float ws[4];
    int tid = blockIdx.x * 256 + threadIdx.x;
    float lsum = 0.0f;
    #pragma unroll
    for (int rep = 0; rep < 4; ++rep) {
        size_t q = (size_t)tid + (size_t)rep * 262144;
        float4 rv = *reinterpret_cast<float4*>(rq + q * 4);
        float4 xv = *reinterpret_cast<const float4*>(x + q * 4);
        lsum += rv.x*rv.x + rv.y*rv.y + rv.z*rv.z + rv.w*rv.w;
        float4 o = {xv.x - rv.x, xv.y - rv.y, xv.z - rv.z, xv.w - rv.w};
        *reinterpret_cast<float4*>(rq + q * 4) = o;
    }
    #pragma unroll
    for (int off = 32; off > 0; off >>= 1) lsum += __shfl_down(lsum, off, 64);
    if ((threadIdx.x & 63) == 0) ws[threadIdx.x >> 6] = lsum;
    __syncthreads();
    if (threadIdx.x == 0) atomicAdd(loss_acc, ws[0] + ws[1] + ws[2] + ws[3]);
}

__global__ void rvq_fin_rmw(const float* __restrict__ rm_in,
                            float* __restrict__ rm_io,
                            const float* __restrict__ ws_rm,
                            int nrep_m1,
                            float* __restrict__ w_out,
                            const float* __restrict__ cc_fin,
                            const float* __restrict__ loss_acc,
                            float* __restrict__ loss_out) {
    int i = blockIdx.x * 256 + threadIdx.x;
    float a = rm_io[i];
    for (int r = 0; r < nrep_m1; ++r) a += ws_rm[(size_t)r * SZ_W + i];
    float nrm = rm_in[i] * 0.99f + (a / 32768.0f) * 0.01f;
    rm_io[i] = nrm;
    w_out[i] = nrm / (1e-10f + cc_fin[i >> 7]);
    if (i == 0) loss_out[0] = loss_acc[0] / (float)(NTOK * DIMS);
}

extern "C" void kernel_launch(void* const* d_in, const int* in_sizes, int n_in,
                              void* d_out, int out_size, void* d_ws, size_t ws_size,
                              hipStream_t stream) {
    const float* x   = (const float*)d_in[0];
    const float* w   = (const float*)d_in[1];
    const float* rm  = (const float*)d_in[2];
    const float* cc  = (const float*)d_in[3];
    float* out   = (float*)d_out;
    float* quant = out;
    float* codes = out + OFF_CODES;
    float* loss  = out + OFF_LOSS;
    float* wout  = out + OFF_W;
    float* rmout = out + OFF_RM;
    float* ccout = out + OFF_CC;
    float* wsf   = (float*)d_ws;
    float* lacc  = wsf;
    int*   flagcnt = (int*)(wsf) + 8;           // 8 per-stage slots
    float* wsq   = wsf + WS_WSQ;
    int*   kidx  = (int*)(wsf + WS_KIDX);
    int*   cursor= (int*)(wsf + WS_CUR);
    int*   sorted= (int*)(wsf + WS_SORT);
    int*   flaglist = (int*)(wsf + WS_FLAG);
    float4* top2 = (float4*)(wsf + WS_TOP2);
    unsigned short* wsplit = (unsigned short*)(wsf + WS_WSPLIT);
    float* repbuf= wsf + WS_RREP;

    int nrep = 1;
    if (ws_size >= (size_t)(WS_RREP + 2 * SZ_W) * sizeof(float)) nrep = 3;

    hipMemsetAsync(rmout, 0, (size_t)SZ_W * sizeof(float), stream);
    hipMemsetAsync(d_ws, 0, 16 * sizeof(float), stream);  // lacc + 8 flagcnt slots
    if (nrep > 1)
        hipMemsetAsync(repbuf, 0, (size_t)2 * SZ_W * sizeof(float), stream);

    rvq_wsq<<<QST * KC / 4, 256, 0, stream>>>(w, wsq);
    rvq_prep_wsplit<<<QST * CELLS_PER_STAGE / 256, 256, 0, stream>>>(w, wsq, wsplit);

    for (int s = 0; s < QST; ++s) {
        const float* rin = (s == 0) ? x : quant;
        rvq_dist_mfma<<<NTOK / 128 * 2, 256, 0, stream>>>(
            rin,
            wsplit + (size_t)s * CELLS_PER_STAGE * 8,
            top2);
        rvq_merge<<<NTOK / 64, 256, 0, stream>>>(
            top2, rin, quant,
            w + (size_t)s * KC * DIMS,
            codes, kidx, flaglist, flagcnt + s, s);
        rvq_rescore2<<<256, 256, 0, stream>>>(
            quant,
            w + (size_t)s * KC * DIMS,
            wsq + (size_t)s * KC,
            flaglist, flagcnt + s, kidx, codes, s);
        rvq_histscan<<<1, 1024, 0, stream>>>(kidx, cursor, cc, ccout, s);
        rvq_scatter<<<128, 256, 0, stream>>>(kidx, cursor, sorted);
        rvq_segsum<<<NTOK / 64, 128, 0, stream>>>(
            quant, sorted,
            w + (size_t)s * KC * DIMS,
            rmout + (size_t)s * KC * DIMS,
            repbuf + (size_t)s * KC * DIMS,
            nrep);
    }

    rvq_quant_loss<<<1024, 256, 0, stream>>>(x, quant, lacc);
    rvq_fin_rmw<<<SZ_W / 256, 256, 0, stream>>>(rm, rmout, repbuf, nrep - 1,
                                                wout, ccout, lacc, loss);
}

// Round 19
// 730.649 us; speedup vs baseline: 1.1772x; 1.0939x over previous
//
#include <hip/hip_runtime.h>
#include <math.h>

#define NTOK   32768
#define DIMS   128
#define QST    8
#define KC     1024

#define SZ_QUANT (NTOK*DIMS)
#define SZ_CODES (NTOK*QST)
#define SZ_W     (QST*KC*DIMS)
#define OFF_CODES (SZ_QUANT)
#define OFF_LOSS  (OFF_CODES + SZ_CODES)
#define OFF_W     (OFF_LOSS + 1)
#define OFF_RM    (OFF_W + SZ_W)
#define OFF_CC    (OFF_RM + SZ_W)

#define MARGIN 0.02f            // 400 sigma of split-bf16 score error; top-2 exact verify
#define NKC 66                  // 528/8 fragment cells per code
#define CELLS_PER_CT (NKC*32)   // 2112 cells (16B each) per 32-code tile
#define CELLS_PER_STAGE (32*CELLS_PER_CT)
#define WSPLIT_FLOATS (QST*CELLS_PER_STAGE*4)

// d_ws float layout: (R15 layout)
#define WS_WSQ  16
#define WS_KIDX (WS_WSQ + QST*KC)
#define WS_HIST (WS_KIDX + NTOK)
#define WS_CUR  (WS_HIST + KC)
#define WS_SORT (WS_CUR + KC)
#define WS_FLAG (WS_SORT + NTOK)
#define WS_TOP2 (WS_FLAG + NTOK)
#define WS_WSPLIT (WS_TOP2 + 8*NTOK)
#define WS_RREP (WS_WSPLIT + WSPLIT_FLOATS)

typedef __attribute__((address_space(3))) float  lds_f;
typedef const __attribute__((address_space(1))) float gbl_f;
typedef __attribute__((ext_vector_type(8)))  short bf16x8;
typedef __attribute__((ext_vector_type(16))) float f32x16;

__device__ __forceinline__ unsigned short f2bf(float x) {
    unsigned int u = __float_as_uint(x);
    unsigned int r = (u + 0x7fffu + ((u >> 16) & 1u)) >> 16;
    return (unsigned short)r;
}
__device__ __forceinline__ float bf2f(unsigned short h) {
    return __uint_as_float(((unsigned int)h) << 16);
}

// ||w||^2 per code row (all stages)
__global__ void rvq_wsq(const float* __restrict__ w, float* __restrict__ wsq) {
    int row  = blockIdx.x * 4 + (threadIdx.x >> 6);
    int lane = threadIdx.x & 63;
    const float* wr = w + (size_t)row * DIMS;
    float a = wr[lane];
    float b = wr[lane + 64];
    float v = a * a + b * b;
    #pragma unroll
    for (int off = 32; off > 0; off >>= 1) v += __shfl_down(v, off, 64);
    if (lane == 0) wsq[row] = v;
}

// Build wsplit: per (s, ct, kc, code) a 16B cell of 8 bf16.
// Code-side K layout: [0,128)=hi(w) [128,256)=hi(w) [256,384)=lo(w) [384,512)=lo(w)
//                     k=512..514: 3-term bf16 split of -wsq/2 ; rest 0.
__global__ __launch_bounds__(256)
void rvq_prep_wsplit(const float* __restrict__ w, const float* __restrict__ wsq,
                     unsigned short* __restrict__ wsplit) {
    int cell = blockIdx.x * 256 + threadIdx.x;   // [0, 540672)
    int code = cell & 31;
    int c2   = cell >> 5;
    int kc   = c2 % NKC;
    int c3   = c2 / NKC;
    int ct   = c3 & 31;
    int s    = c3 >> 5;
    unsigned short out[8];
    int k0 = kc * 8;
    if (k0 < 512) {
        int region = k0 >> 7;           // 0,1 -> hi ; 2,3 -> lo
        int d0 = k0 & 127;
        const float* wr = w + ((size_t)s * KC + ct * 32 + code) * DIMS + d0;
        #pragma unroll
        for (int e = 0; e < 8; ++e) {
            float v = wr[e];
            unsigned short hu = f2bf(v);
            out[e] = (region < 2) ? hu : f2bf(v - bf2f(hu));
        }
    } else if (kc == 64) {
        float tq = -0.5f * wsq[s * KC + ct * 32 + code];
        unsigned short a = f2bf(tq);
        float fa = bf2f(a);
        unsigned short b = f2bf(tq - fa);
        float fb = bf2f(b);
        unsigned short c = f2bf(tq - fa - fb);
        out[0] = a; out[1] = b; out[2] = c;
        out[3] = out[4] = out[5] = out[6] = out[7] = 0;
    } else {
        #pragma unroll
        for (int e = 0; e < 8; ++e) out[e] = 0;
    }
    unsigned short* dst = wsplit + (size_t)cell * 8;
    #pragma unroll
    for (int e = 0; e < 8; ++e) dst[e] = out[e];
}

// MFMA distance + per-half top-2. Grid 512: blockIdx = tok_blk*2 + ch.
// Block = 256 thr = 4 waves; wave owns 32 tokens; block scans 16 tiles (512 codes).
// 2 blocks/CU (LDS 67.5 KB) -> 2 waves/SIMD for latency hiding.
__global__ __launch_bounds__(256, 2)
void rvq_dist_mfma(const float* __restrict__ rin,
                   const unsigned short* __restrict__ wsp,   // this stage's cells
                   float4* __restrict__ top2)                // [2][NTOK]
{
    __shared__ bf16x8 AT[2][CELLS_PER_CT];   // 2 x 33792 B

    const int bid  = blockIdx.x;
    const int ch   = bid & 1;            // code half: tiles ch*16 .. ch*16+15
    const int tb   = bid >> 1;
    const int t    = threadIdx.x;
    const int lane = t & 63;
    const int wid  = t >> 6;
    const int h    = lane >> 5;          // k-half
    const int ln32 = lane & 31;
    const int token = tb * 128 + wid * 32 + ln32;
    const int gt0  = ch * 16;

    // ---- load this lane's token data (its parity's 8 d-blocks) and build B-frags
    const float* rrow = rin + (size_t)token * DIMS;
    float4 R[16];
    #pragma unroll
    for (int j = 0; j < 8; ++j) {
        int d0 = (2 * j + h) * 8;
        R[2 * j]     = *reinterpret_cast<const float4*>(rrow + d0);
        R[2 * j + 1] = *reinterpret_cast<const float4*>(rrow + d0 + 4);
    }
    bf16x8 hb[8], lb[8];
    #pragma unroll
    for (int j = 0; j < 8; ++j) {
        float v[8] = {R[2*j].x, R[2*j].y, R[2*j].z, R[2*j].w,
                      R[2*j+1].x, R[2*j+1].y, R[2*j+1].z, R[2*j+1].w};
        #pragma unroll
        for (int e = 0; e < 8; ++e) {
            unsigned short hu = f2bf(v[e]);
            hb[j][e] = (short)hu;
            lb[j][e] = (short)f2bf(v[e] - bf2f(hu));
        }
    }
    // Token-side K layout: [0,128)=hi [128,256)=lo [256,384)=hi [384,512)=lo ; 512..514: 1.0
    bf16x8 bfr[33];
    #pragma unroll
    for (int fs = 0; fs < 32; ++fs) {
        int j = fs & 7;
        int region = fs >> 3;            // 0,2 -> hi ; 1,3 -> lo
        bfr[fs] = ((region & 1) == 0) ? hb[j] : lb[j];
    }
    {
        bf16x8 ones = {(short)0x3f80, (short)0x3f80, (short)0x3f80, 0, 0, 0, 0, 0};
        bf16x8 zero = {0, 0, 0, 0, 0, 0, 0, 0};
        bfr[32] = (h == 0) ? ones : zero;
    }

    // ---- prologue: stage first tile
    {
        const unsigned short* src = wsp + (size_t)gt0 * CELLS_PER_CT * 8;
        #pragma unroll 1
        for (int i = wid; i < 33; i += 4) {
            __builtin_amdgcn_global_load_lds(
                (gbl_f*)(src + (size_t)i * 512 + lane * 8),
                (lds_f*)((unsigned short*)&AT[0][i * 64]), 16, 0, 0);
        }
        asm volatile("s_waitcnt vmcnt(0)" ::: "memory");
    }
    __syncthreads();

    float b1 = -INFINITY, b2 = -INFINITY;
    int   k1 = 0, k2 = 0;

    #pragma unroll 1
    for (int tt = 0; tt < 16; ++tt) {
        const int buf = tt & 1;
        if (tt < 15) {                        // stage next tile
            const unsigned short* src = wsp + (size_t)(gt0 + tt + 1) * CELLS_PER_CT * 8;
            #pragma unroll 1
            for (int i = wid; i < 33; i += 4) {
                __builtin_amdgcn_global_load_lds(
                    (gbl_f*)(src + (size_t)i * 512 + lane * 8),
                    (lds_f*)((unsigned short*)&AT[buf ^ 1][i * 64]), 16, 0, 0);
            }
        }

        f32x16 acc;
        #pragma unroll
        for (int e = 0; e < 16; ++e) acc[e] = 0.0f;

        const bf16x8* Ab = &AT[buf][lane];    // cell = 64*ks + lane
        #pragma unroll
        for (int ks = 0; ks < 33; ++ks) {
            bf16x8 af = Ab[ks * 64];
            acc = __builtin_amdgcn_mfma_f32_32x32x16_bf16(af, bfr[ks], acc, 0, 0, 0);
        }

        // running top-2 (score = dot - wsq/2 ; maximize)
        #pragma unroll
        for (int r = 0; r < 16; ++r) {
            float sc = acc[r];
            int   kk = (gt0 + tt) * 32 + ((r & 3) + 8 * (r >> 2) + 4 * h);
            bool  gt = sc > b1;
            bool  g2 = sc > b2;
            k2 = gt ? k1 : (g2 ? kk : k2);
            b2 = gt ? b1 : (g2 ? sc : b2);
            k1 = gt ? kk : k1;
            b1 = gt ? sc : b1;
        }

        asm volatile("s_waitcnt vmcnt(0)" ::: "memory");
        __syncthreads();
    }

    // ---- merge the two k-halves of this token (lanes l <-> l+32)
    float ob1 = __shfl_xor(b1, 32, 64);
    float ob2 = __shfl_xor(b2, 32, 64);
    int   ok1 = __shfl_xor(k1, 32, 64);
    int   ok2 = __shfl_xor(k2, 32, 64);
    bool fw = (b1 > ob1) || (b1 == ob1 && k1 < ok1);
    float B1 = fw ? b1 : ob1;  int K1 = fw ? k1 : ok1;
    float c1 = fw ? ob1 : b1;  int c1k = fw ? ok1 : k1;   // loser's top
    float c2 = fw ? b2 : ob2;  int c2k = fw ? k2 : ok2;   // winner's second
    bool sw = (c1 > c2) || (c1 == c2 && c1k < c2k);
    float B2 = sw ? c1 : c2;   int K2 = sw ? c1k : c2k;

    if (h == 0) {
        float4 o = {B1, B2, __int_as_float(K1), __int_as_float(K2)};
        top2[(size_t)ch * NTOK + token] = o;
    }
}

// Merge the two code-half top2s (threads 0-63) + coalesced residual update.
// 512 blocks. No per-token device atomics (flagcnt wave-aggregated).
__global__ __launch_bounds__(256)
void rvq_merge(const float4* __restrict__ top2,
               const float* __restrict__ rin,
               float* __restrict__ rout,
               const float* __restrict__ wst,
               float* __restrict__ codes_out,
               int* __restrict__ kidx,
               int* __restrict__ flaglist,
               int* __restrict__ flagcnt,
               int stage)
{
    __shared__ int kb[64];
    const int t    = threadIdx.x;
    const int tok0 = blockIdx.x * 64;

    if (t < 64) {                         // exactly wave 0
        const int token = tok0 + t;
        float4 a = top2[token];
        float4 b = top2[NTOK + token];
        float a1 = a.x, a2 = a.y; int ak1 = __float_as_int(a.z), ak2 = __float_as_int(a.w);
        float c1 = b.x, c2 = b.y; int bk1 = __float_as_int(b.z), bk2 = __float_as_int(b.w);
        bool fw = (a1 > c1) || (a1 == c1 && ak1 < bk1);
        float B1 = fw ? a1 : c1;  int K1 = fw ? ak1 : bk1;
        float l1 = fw ? c1 : a1;  int l1k = fw ? bk1 : ak1;   // loser's top
        float w2 = fw ? a2 : c2;  int w2k = fw ? ak2 : bk2;   // winner's second
        bool sw = (l1 > w2) || (l1 == w2 && l1k < w2k);
        float B2 = sw ? l1 : w2;  int K2 = sw ? l1k : w2k;

        kidx[token] = K1;
        codes_out[(size_t)token * QST + stage] = (float)K1;
        kb[t] = K1;

        bool flg = (B1 - B2 < MARGIN);
        unsigned long long mask = __ballot(flg);
        int base = 0;
        if (t == 0 && mask) base = atomicAdd(flagcnt, (int)__popcll(mask));
        base = __shfl(base, 0, 64);
        if (flg) {
            int off = (int)__popcll(mask & ((1ULL << t) - 1ULL));
            flaglist[base + off] = (K2 << 15) | token;
        }
    }
    __syncthreads();

    // residual update: rout = rin - w[K1]; 64 tok x 32 float4, coalesced
    #pragma unroll
    for (int it = 0; it < 8; ++it) {
        int idx = it * 256 + t;
        int tok = idx >> 5;
        int dq  = idx & 31;
        int k   = kb[tok];
        float4 rv = *reinterpret_cast<const float4*>(rin + (size_t)(tok0 + tok) * DIMS + dq * 4);
        float4 wv = *reinterpret_cast<const float4*>(wst + (size_t)k * DIMS + dq * 4);
        float4 o = {rv.x - wv.x, rv.y - wv.y, rv.z - wv.z, rv.w - wv.w};
        *reinterpret_cast<float4*>(rout + (size_t)(tok0 + tok) * DIMS + dq * 4) = o;
    }
}

// Exact fp32 top-2 verify for flagged tokens: one wave per token.
// r_old reconstructed as rout + w[k1]; patches kidx/codes/rout on flip.
__global__ __launch_bounds__(256)
void rvq_rescore2(float* __restrict__ rq,
                  const float* __restrict__ wst,
                  const float* __restrict__ wsqst,
                  const int* __restrict__ flaglist,
                  const int* __restrict__ flagcnt,
                  int* __restrict__ kidx,
                  float* __restrict__ codes_out,
                  int stage)
{
    const int cnt  = *flagcnt;
    const int lane = threadIdx.x & 63;
    const int wave = blockIdx.x * 4 + (threadIdx.x >> 6);
    const int nw   = gridDim.x * 4;

    for (int f = wave; f < cnt; f += nw) {
        int e   = flaglist[f];
        int tok = e & 32767;
        int k2  = e >> 15;
        int k1  = kidx[tok];
        float rn0 = rq[(size_t)tok * DIMS + lane];
        float rn1 = rq[(size_t)tok * DIMS + 64 + lane];
        float w10 = wst[(size_t)k1 * DIMS + lane];
        float w11 = wst[(size_t)k1 * DIMS + 64 + lane];
        float w20 = wst[(size_t)k2 * DIMS + lane];
        float w21 = wst[(size_t)k2 * DIMS + 64 + lane];
        float r0 = rn0 + w10, r1 = rn1 + w11;       // r_old
        float d1 = r0 * w10 + r1 * w11;
        float d2 = r0 * w20 + r1 * w21;
        #pragma unroll
        for (int off = 32; off > 0; off >>= 1) {
            d1 += __shfl_xor(d1, off, 64);
            d2 += __shfl_xor(d2, off, 64);
        }
        float s1 = wsqst[k1] - 2.0f * d1;
        float s2 = wsqst[k2] - 2.0f * d2;
        bool flip = (s2 < s1) || (s2 == s1 && k2 < k1);
        if (flip) {
            rq[(size_t)tok * DIMS + lane]      = r0 - w20;
            rq[(size_t)tok * DIMS + 64 + lane] = r1 - w21;
            if (lane == 0) {
                kidx[tok] = k2;
                codes_out[(size_t)tok * QST + stage] = (float)k2;
            }
        }
    }
}

// Histogram of final codes: 32 blocks x 256 threads, LDS-privatized
// (hottest bin <= 32 device atomics). Global hist zero on entry; scan re-zeroes.
__global__ __launch_bounds__(256)
void rvq_histo(const int* __restrict__ kidx, int* __restrict__ hist) {
    __shared__ int lh[KC];
    const int t = threadIdx.x;
    #pragma unroll
    for (int rep = 0; rep < 4; ++rep) lh[rep * 256 + t] = 0;
    __syncthreads();
    int base = blockIdx.x * 1024;
    #pragma unroll
    for (int rep = 0; rep < 4; ++rep) {
        int k = kidx[base + rep * 256 + t];
        atomicAdd(&lh[k], 1);
    }
    __syncthreads();
    #pragma unroll
    for (int rep = 0; rep < 4; ++rep) {
        int bin = rep * 256 + t;
        int c = lh[bin];
        if (c) atomicAdd(&hist[bin], c);
    }
}

// Exclusive scan of hist -> cursor; finalizes code_count; re-zeroes hist.
__global__ __launch_bounds__(1024)
void rvq_scan(int* __restrict__ hist, int* __restrict__ cursor,
              const float* __restrict__ cc_in, float* __restrict__ cc_io,
              int stage) {
    __shared__ int s[KC];
    const int t = threadIdx.x;
    int h = hist[t];
    hist[t] = 0;                          // ready for next stage
    s[t] = h;
    __syncthreads();
    for (int off = 1; off < KC; off <<= 1) {
        int v = (t >= off) ? s[t - off] : 0;
        __syncthreads();
        s[t] += v;
        __syncthreads();
    }
    cursor[t] = s[t] - h;
    size_t gi = (size_t)stage * KC + t;
    cc_io[gi] = cc_in[gi] * 0.99f + ((float)h / 32768.0f) * 0.01f;
}

// Rank-based counting-sort scatter: 128 blocks x 256 threads.
__global__ __launch_bounds__(256)
void rvq_scatter(const int* __restrict__ kidx, int* __restrict__ cursor,
                 int* __restrict__ sorted) {
    __shared__ int lh[KC];
    __shared__ int lb[KC];
    const int t = threadIdx.x;
    #pragma unroll
    for (int rep = 0; rep < 4; ++rep) lh[rep * 256 + t] = 0;
    __syncthreads();
    int tok = blockIdx.x * 256 + t;
    int k   = kidx[tok];
    int lr  = atomicAdd(&lh[k], 1);
    __syncthreads();
    #pragma unroll
    for (int rep = 0; rep < 4; ++rep) {
        int bin = rep * 256 + t;
        int c = lh[bin];
        if (c) lb[bin] = atomicAdd(&cursor[bin], c);
    }
    __syncthreads();
    int pos = lb[k] + lr;
    sorted[pos] = (k << 15) | tok;
}

// Segmented sum over sorted tokens, reconstructing r_old = r_new + w[k]:
// sum(r_old over run) = sum(r_new) + count*w[k]. Run-boundary atomics only.
__global__ __launch_bounds__(128)
void rvq_segsum(const float* __restrict__ rq,
                const int* __restrict__ sorted,
                const float* __restrict__ wst,
                float* __restrict__ rm0,
                float* __restrict__ repbuf,
                int nrep)
{
    __shared__ int pc[64];
    const int t = threadIdx.x;
    if (t < 64) pc[t] = sorted[blockIdx.x * 64 + t];
    __syncthreads();

    int rep = (int)(blockIdx.x % (unsigned)nrep);
    float* rmt = (rep == 0) ? rm0 : repbuf + (size_t)(rep - 1) * SZ_W;

    const int d = t;
    int   cur = pc[0] >> 15;
    float acc = 0.0f;
    float lc  = 0.0f;
    #pragma unroll 4
    for (int i = 0; i < 64; ++i) {
        int v   = pc[i];
        int c   = v >> 15;
        int tok = v & 32767;
        if (c != cur) {
            atomicAdd(rmt + (size_t)cur * DIMS + d,
                      acc + lc * wst[(size_t)cur * DIMS + d]);
            acc = 0.0f; lc = 0.0f;
            cur = c;
        }
        acc += rq[(size_t)tok * DIMS + d];
        lc  += 1.0f;
    }
    atomicAdd(rmt + (size_t)cur * DIMS + d,
              acc + lc * wst[(size_t)cur * DIMS + d]);
}

// quantized = x - r (in place) + commitment-loss partials
__global__ void rvq_quant_loss(const float* __restrict__ x,
                               float* __restrict__ rq,
                               float* __restrict__ loss_acc) {
    __shared__ float ws[4];
    int tid = blockIdx.x * 256 + threadIdx.x;
    float lsum = 0.0f;
    #pragma unroll
    for (int rep = 0; rep < 4; ++rep) {
        size_t q = (size_t)tid + (size_t)rep * 262144;
        float4 rv = *reinterpret_cast<float4*>(rq + q * 4);
        float4 xv = *reinterpret_cast<const float4*>(x + q * 4);
        lsum += rv.x*rv.x + rv.y*rv.y + rv.z*rv.z + rv.w*rv.w;
        float4 o = {xv.x - rv.x, xv.y - rv.y, xv.z - rv.z, xv.w - rv.w};
        *reinterpret_cast<float4*>(rq + q * 4) = o;
    }
    #pragma unroll
    for (int off = 32; off > 0; off >>= 1) lsum += __shfl_down(lsum, off, 64);
    if ((threadIdx.x & 63) == 0) ws[threadIdx.x >> 6] = lsum;
    __syncthreads();
    if (threadIdx.x == 0) atomicAdd(loss_acc, ws[0] + ws[1] + ws[2] + ws[3]);
}

__global__ void rvq_fin_rmw(const float* __restrict__ rm_in,
                            float* __restrict__ rm_io,
                            const float* __restrict__ ws_rm,
                            int nrep_m1,
                            float* __restrict__ w_out,
                            const float* __restrict__ cc_fin,
                            const float* __restrict__ loss_acc,
                            float* __restrict__ loss_out) {
    int i = blockIdx.x * 256 + threadIdx.x;
    float a = rm_io[i];
    for (int r = 0; r < nrep_m1; ++r) a += ws_rm[(size_t)r * SZ_W + i];
    float nrm = rm_in[i] * 0.99f + (a / 32768.0f) * 0.01f;
    rm_io[i] = nrm;
    w_out[i] = nrm / (1e-10f + cc_fin[i >> 7]);
    if (i == 0) loss_out[0] = loss_acc[0] / (float)(NTOK * DIMS);
}

extern "C" void kernel_launch(void* const* d_in, const int* in_sizes, int n_in,
                              void* d_out, int out_size, void* d_ws, size_t ws_size,
                              hipStream_t stream) {
    const float* x   = (const float*)d_in[0];
    const float* w   = (const float*)d_in[1];
    const float* rm  = (const float*)d_in[2];
    const float* cc  = (const float*)d_in[3];
    float* out   = (float*)d_out;
    float* quant = out;
    float* codes = out + OFF_CODES;
    float* loss  = out + OFF_LOSS;
    float* wout  = out + OFF_W;
    float* rmout = out + OFF_RM;
    float* ccout = out + OFF_CC;
    float* wsf   = (float*)d_ws;
    float* lacc  = wsf;
    int*   flagcnt = (int*)(wsf) + 8;           // 8 per-stage slots
    float* wsq   = wsf + WS_WSQ;
    int*   kidx  = (int*)(wsf + WS_KIDX);
    int*   hist  = (int*)(wsf + WS_HIST);
    int*   cursor= (int*)(wsf + WS_CUR);
    int*   sorted= (int*)(wsf + WS_SORT);
    int*   flaglist = (int*)(wsf + WS_FLAG);
    float4* top2 = (float4*)(wsf + WS_TOP2);
    unsigned short* wsplit = (unsigned short*)(wsf + WS_WSPLIT);
    float* repbuf= wsf + WS_RREP;

    int nrep = 1;
    if (ws_size >= (size_t)(WS_RREP + 2 * SZ_W) * sizeof(float)) nrep = 3;

    hipMemsetAsync(rmout, 0, (size_t)SZ_W * sizeof(float), stream);
    hipMemsetAsync(d_ws, 0, 16 * sizeof(float), stream);  // lacc + 8 flagcnt slots
    hipMemsetAsync(hist, 0, KC * sizeof(int), stream);    // once; scan re-zeroes
    if (nrep > 1)
        hipMemsetAsync(repbuf, 0, (size_t)2 * SZ_W * sizeof(float), stream);

    rvq_wsq<<<QST * KC / 4, 256, 0, stream>>>(w, wsq);
    rvq_prep_wsplit<<<QST * CELLS_PER_STAGE / 256, 256, 0, stream>>>(w, wsq, wsplit);

    for (int s = 0; s < QST; ++s) {
        const float* rin = (s == 0) ? x : quant;
        rvq_dist_mfma<<<NTOK / 128 * 2, 256, 0, stream>>>(
            rin,
            wsplit + (size_t)s * CELLS_PER_STAGE * 8,
            top2);
        rvq_merge<<<NTOK / 64, 256, 0, stream>>>(
            top2, rin, quant,
            w + (size_t)s * KC * DIMS,
            codes, kidx, flaglist, flagcnt + s, s);
        rvq_rescore2<<<256, 256, 0, stream>>>(
            quant,
            w + (size_t)s * KC * DIMS,
            wsq + (size_t)s * KC,
            flaglist, flagcnt + s, kidx, codes, s);
        rvq_histo<<<32, 256, 0, stream>>>(kidx, hist);
        rvq_scan<<<1, 1024, 0, stream>>>(hist, cursor, cc, ccout, s);
        rvq_scatter<<<128, 256, 0, stream>>>(kidx, cursor, sorted);
        rvq_segsum<<<NTOK / 64, 128, 0, stream>>>(
            quant, sorted,
            w + (size_t)s * KC * DIMS,
            rmout + (size_t)s * KC * DIMS,
            repbuf + (size_t)s * KC * DIMS,
            nrep);
    }

    rvq_quant_loss<<<1024, 256, 0, stream>>>(x, quant, lacc);
    rvq_fin_rmw<<<SZ_W / 256, 256, 0, stream>>>(rm, rmout, repbuf, nrep - 1,
                                                wout, ccout, lacc, loss);
}